// Round 24
// baseline (260.280 us; speedup 1.0000x reference)
//
#include <hip/hip_runtime.h>
#include <hip/hip_bf16.h>
#include <math.h>

#define N_NODES 100000
#define E_EDGES 1600000
#define ETOT    (E_EDGES + N_NODES)
#define NEG     0.2f

// bucketed CSR build
#define SH        8
#define NBUCK     ((N_NODES + 255) >> 8)          // 391
#define BIN_TILE  4096
#define NBIN      ((E_EDGES + BIN_TILE - 1) / BIN_TILE)  // 391
#define CAP_B     5120                            // per-bucket COO capacity
#define DBINS     64                              // degree bins (clamped)

#define NMFMA     ((N_NODES + 63) / 64)           // 1563
#define G_A       782                             // gemm blocks fused with bin
#define G_B       (NMFMA - G_A)                   // 781, fused with fine
#define NODE_BLK  ((N_NODES + 255) / 256)         // 391

typedef __attribute__((ext_vector_type(8))) short bf16x8;
typedef __attribute__((ext_vector_type(4))) float f32x4;
typedef __attribute__((ext_vector_type(2))) short bf16p;

__device__ inline float lrelu(float x) { return x > 0.f ? x : NEG * x; }
__device__ inline float bflo(unsigned int b) { return __uint_as_float(b << 16); }
__device__ inline float bfhi(unsigned int b) { return __uint_as_float(b & 0xFFFF0000u); }
__device__ inline unsigned short f2bf(float f) {   // RNE bf16 bits
    unsigned int u = __float_as_uint(f);
    return (unsigned short)((u + 0x7FFFu + ((u >> 16) & 1u)) >> 16);
}

// dot of 2 bf16 pairs with f32 accumulate
__device__ inline float dot2bf(unsigned int wp, unsigned int hp, float c) {
#if __has_builtin(__builtin_amdgcn_fdot2_f32_bf16)
    return __builtin_amdgcn_fdot2_f32_bf16(__builtin_bit_cast(bf16p, wp),
                                           __builtin_bit_cast(bf16p, hp),
                                           c, false);
#else
    return fmaf(bflo(wp), bflo(hp), fmaf(bfhi(wp), bfhi(hp), c));
#endif
}

// exclusive scan over 256 threads: wave shfl scan + 1 barrier. wscr = int[4].
__device__ inline int exscan256(int v, int* wscr, int t) {
    int lane = t & 63, wid = t >> 6;
    int incl = v;
#pragma unroll
    for (int ofs = 1; ofs < 64; ofs <<= 1) {
        int u = __shfl_up(incl, ofs, 64);
        if (lane >= ofs) incl += u;
    }
    if (lane == 63) wscr[wid] = incl;
    __syncthreads();
    int wpre = 0;
#pragma unroll
    for (int w = 0; w < 4; ++w) wpre += (w < wid) ? wscr[w] : 0;
    return wpre + incl - v;
}

// ---------------- W1^T -> bf16 (one-off, 32 KB) -----------------------------
__global__ __launch_bounds__(256) void k_wt(const float* __restrict__ W,
                                            unsigned short* __restrict__ wtg) {
    int t = blockIdx.x * 256 + threadIdx.x;   // t = n*128 + k
    if (t >= 128 * 128) return;
    int n = t >> 7, k = t & 127;
    wtg[t] = f2bf(W[k * 128 + n]);
}

// ---------------- gemm1 role (device fn): 64 nodes per block ----------------
__device__ __forceinline__ void gemm1_role(
    int n0, int t, unsigned short (*xb)[136],
    const float* __restrict__ x, const unsigned short* __restrict__ wtg,
    const float* __restrict__ asrc, const float* __restrict__ adst,
    __hip_bfloat16* __restrict__ h1b, unsigned short* __restrict__ s1b,
    float* __restrict__ d1) {
#pragma unroll
    for (int i = 0; i < 8; ++i) {
        int i4 = t + i * 256;
        int r = i4 >> 5;
        int c = (i4 & 31) * 4;
        float4 v = make_float4(0.f, 0.f, 0.f, 0.f);
        if (n0 + r < N_NODES) v = *(const float4*)(x + (size_t)(n0 + r) * 128 + c);
        xb[r][c + 0] = f2bf(v.x);
        xb[r][c + 1] = f2bf(v.y);
        xb[r][c + 2] = f2bf(v.z);
        xb[r][c + 3] = f2bf(v.w);
    }
    __syncthreads();

    int l = t & 63, wv = t >> 6;
    int col = l & 15, q4 = l >> 4;
    int rbase = wv * 16;
    int koff = q4 * 8;

    bf16x8 a[4];
#pragma unroll
    for (int st = 0; st < 4; ++st)
        a[st] = *(const bf16x8*)&xb[rbase + col][st * 32 + koff];

    int nodeb = n0 + rbase + q4 * 4;
#pragma unroll
    for (int nt = 0; nt < 8; ++nt) {
        f32x4 acc = {0.f, 0.f, 0.f, 0.f};
        const unsigned short* wrow = wtg + (size_t)(nt * 16 + col) * 128 + koff;
#pragma unroll
        for (int st = 0; st < 4; ++st) {
            bf16x8 b = *(const bf16x8*)(wrow + st * 32);
            acc = __builtin_amdgcn_mfma_f32_16x16x32_bf16(a[st], b, acc, 0, 0, 0);
        }
        float as_v = asrc[nt * 16 + col];
        float ad_v = adst[nt * 16 + col];
#pragma unroll
        for (int r = 0; r < 4; ++r) {
            int node = nodeb + r;
            if (node < N_NODES)
                h1b[(size_t)node * 128 + nt * 16 + col] = __float2bfloat16(acc[r]);
            float ps = acc[r] * as_v, pd = acc[r] * ad_v;
#pragma unroll
            for (int ofs = 1; ofs < 16; ofs <<= 1) {
                ps += __shfl_xor(ps, ofs, 64);
                pd += __shfl_xor(pd, ofs, 64);
            }
            if (col == 0 && node < N_NODES) {
                s1b[node * 8 + nt] = f2bf(ps);
                d1[node * 8 + nt] = pd;
            }
        }
    }
}

// ---------------- kernel: bin (bucket-major COO) || gemm1 part A ------------
union SmemBin {
    struct {
        int2 st[BIN_TILE];
        int  hist[NBUCK + 1];
        int  lstart[NBUCK];
        int  gbase[NBUCK];
        int  wscr[4];
    } b;
    unsigned short xb[64][136];
};

__global__ __launch_bounds__(256) void k_parBin(
    const int* __restrict__ src, const int* __restrict__ dst,
    int* __restrict__ gcur, int2* __restrict__ coo,
    const float* __restrict__ x, const unsigned short* __restrict__ wtg,
    const float* __restrict__ asrc, const float* __restrict__ adst,
    __hip_bfloat16* __restrict__ h1b, unsigned short* __restrict__ s1b,
    float* __restrict__ d1) {
    __shared__ SmemBin sm;
    int bid = blockIdx.x, t = threadIdx.x;
    bool isBin = (bid % 3 == 0) && (bid / 3 < NBIN);
    if (!isBin) {                       // gemm role, gid 0..G_A-1
        int gid = bid - bid / 3 - 1;
        gemm1_role(gid * 64, t, sm.xb, x, wtg, asrc, adst, h1b, s1b, d1);
        return;
    }
    int wb = bid / 3;                   // bin tile 0..NBIN-1
    int e0 = wb * BIN_TILE;
    int nE = min(BIN_TILE, E_EDGES - e0);
    for (int i = t; i <= NBUCK; i += 256) sm.b.hist[i] = 0;
    __syncthreads();
    for (int i = t; i < nE; i += 256)
        atomicAdd(&sm.b.hist[dst[e0 + i] >> SH], 1);
    __syncthreads();
    int i0 = 2 * t, i1 = 2 * t + 1;
    int h0 = (i0 < NBUCK) ? sm.b.hist[i0] : 0;
    int h1v = (i1 < NBUCK) ? sm.b.hist[i1] : 0;
    int s = h0 + h1v;
    int pre = exscan256(s, sm.b.wscr, t);
    __syncthreads();
    if (i0 < NBUCK) sm.b.hist[i0] = pre;
    if (i1 < NBUCK) sm.b.hist[i1] = pre + h0;
    if (t == 255) sm.b.hist[NBUCK] = pre + s;
    __syncthreads();
    for (int i = t; i < NBUCK; i += 256) {
        int st_ = sm.b.hist[i];
        int cnt = sm.b.hist[i + 1] - st_;
        sm.b.lstart[i] = st_;
        if (cnt > 0) sm.b.gbase[i] = i * CAP_B + atomicAdd(&gcur[i], cnt);
    }
    __syncthreads();
    for (int i = t; i < nE; i += 256) {
        int sv = src[e0 + i], dv = dst[e0 + i];
        int p = atomicAdd(&sm.b.hist[dv >> SH], 1);
        sm.b.st[p] = make_int2(sv, dv);
    }
    __syncthreads();
    for (int i = t; i < nE; i += 256) {
        int2 e = sm.b.st[i];
        int b2 = e.y >> SH;
        int slot = sm.b.gbase[b2] + (i - sm.b.lstart[b2]);
        slot = min(slot, (b2 + 1) * CAP_B - 1);   // overflow clamp
        coo[slot] = e;
    }
}

// ---------------- scanb: 391 bucket totals -> bbase; off[N]=ETOT ------------
__global__ __launch_bounds__(256) void k_scanb(const int* __restrict__ gcur,
                                               int* __restrict__ bbase,
                                               int* __restrict__ off) {
    __shared__ int wscr[4];
    int t = threadIdx.x;
    int i0 = 2 * t, i1 = 2 * t + 1;
    int a = 0, b = 0;
    if (i0 < NBUCK) a = min(gcur[i0], CAP_B) + min(256, N_NODES - (i0 << SH));
    if (i1 < NBUCK) b = min(gcur[i1], CAP_B) + min(256, N_NODES - (i1 << SH));
    int s = a + b;
    int pre = exscan256(s, wscr, t);
    if (i0 < NBUCK) bbase[i0] = pre;
    if (i1 < NBUCK) bbase[i1] = pre + a;
    if (t == 0) off[N_NODES] = ETOT;
}

// ---------------- kernel: fine (LDS reorder) || gemm1 part B ----------------
union SmemFine {
    struct {
        int ldeg[256];
        int lsrc[CAP_B + 256];
        int wscr[4];
    } f;
    unsigned short xb[64][136];
};

__global__ __launch_bounds__(256) void k_parFine(
    const int2* __restrict__ coo, const int* __restrict__ gcur,
    const int* __restrict__ bbase, int* __restrict__ off,
    int* __restrict__ csr,
    const float* __restrict__ x, const unsigned short* __restrict__ wtg,
    const float* __restrict__ asrc, const float* __restrict__ adst,
    __hip_bfloat16* __restrict__ h1b, unsigned short* __restrict__ s1b,
    float* __restrict__ d1) {
    __shared__ SmemFine sm;
    int bid = blockIdx.x, t = threadIdx.x;
    bool isFine = (bid % 3 == 0) && (bid / 3 < NBUCK);
    if (!isFine) {                      // gemm role, gid 0..G_B-1
        int gid = bid - bid / 3 - 1;
        gemm1_role((G_A + gid) * 64, t, sm.xb, x, wtg, asrc, adst,
                   h1b, s1b, d1);
        return;
    }
    int b = bid / 3;
    int n0 = b << SH;
    int nn = min(256, N_NODES - n0);
    int ecnt = min(gcur[b], CAP_B);
    int base = bbase[b];
    const int2* seg = coo + (size_t)b * CAP_B;

    sm.f.ldeg[t] = 0;
    __syncthreads();
    for (int i = t; i < ecnt; i += 256)
        atomicAdd(&sm.f.ldeg[seg[i].y - n0], 1);
    __syncthreads();
    int d = (t < nn) ? sm.f.ldeg[t] + 1 : 0;   // +1 self-loop
    int myoff = exscan256(d, sm.f.wscr, t);
    __syncthreads();
    if (t < nn) {
        off[n0 + t] = base + myoff;
        sm.f.lsrc[myoff] = n0 + t;
        sm.f.ldeg[t] = myoff + 1;
    }
    __syncthreads();
    for (int i = t; i < ecnt; i += 256) {
        int2 e = seg[i];
        int p = atomicAdd(&sm.f.ldeg[e.y - n0], 1);
        sm.f.lsrc[p] = e.x;
    }
    __syncthreads();
    int tot = ecnt + nn;
    for (int i = t; i < tot; i += 256)
        csr[base + i] = sm.f.lsrc[i];
}

// ---------------- degree-sorted permutation (3 tiny kernels) ----------------
__global__ __launch_bounds__(256) void k_dcnt(const int* __restrict__ off,
                                              int* __restrict__ dhist) {
    __shared__ int lh[DBINS];
    int t = threadIdx.x;
    int n = blockIdx.x * 256 + t;
    if (t < DBINS) lh[t] = 0;
    __syncthreads();
    if (n < N_NODES) {
        int bin = min(off[n + 1] - off[n], DBINS - 1);
        atomicAdd(&lh[bin], 1);
    }
    __syncthreads();
    if (t < DBINS && lh[t] > 0) atomicAdd(&dhist[t], lh[t]);
}

__global__ void k_dbase(const int* __restrict__ dhist, int* __restrict__ dcur) {
    int t = threadIdx.x;   // 64
    int v = dhist[t];
    int incl = v;
#pragma unroll
    for (int ofs = 1; ofs < 64; ofs <<= 1) {
        int u = __shfl_up(incl, ofs, 64);
        if (t >= ofs) incl += u;
    }
    dcur[t] = incl - v;    // exclusive prefix
}

__global__ __launch_bounds__(256) void k_dscat(const int* __restrict__ off,
                                               int* __restrict__ dcur,
                                               int* __restrict__ perm) {
    __shared__ int lh[DBINS], lbase[DBINS];
    int t = threadIdx.x;
    int n = blockIdx.x * 256 + t;
    if (t < DBINS) lh[t] = 0;
    __syncthreads();
    int bin = 0, lr = 0;
    bool valid = (n < N_NODES);
    if (valid) {
        bin = min(off[n + 1] - off[n], DBINS - 1);
        lr = atomicAdd(&lh[bin], 1);
    }
    __syncthreads();
    if (t < DBINS && lh[t] > 0) lbase[t] = atomicAdd(&dcur[t], lh[t]);
    __syncthreads();
    if (valid) perm[lbase[bin] + lr] = n;
}

// ---------------- layer 1 softmax-aggregate + fused gemm2 (LDS handoff) -----
__global__ __launch_bounds__(256) void k_l1(
    const int* __restrict__ perm,
    const int* __restrict__ off, const int* __restrict__ csr,
    const unsigned short* __restrict__ s1b, const float* __restrict__ d1,
    const uint4* __restrict__ h1q, const float* __restrict__ b1,
    float* __restrict__ emb,
    const float* __restrict__ W2, const float* __restrict__ as2,
    const float* __restrict__ ad2, unsigned short* __restrict__ h2s,
    float* __restrict__ s2, float* __restrict__ d2v) {
    __shared__ float esh[4][128];
    int t = threadIdx.x;
    int node = perm[(blockIdx.x << 2) + (t >> 6)];
    int wv = t >> 6;
    int l = t & 63;
    int g = l >> 4, q = l & 15;
    int hb = q >> 1;
    int lo = off[node], hi = off[node + 1];
    float dvh = d1[node * 8 + hb];

    float acc[8];
#pragma unroll
    for (int c = 0; c < 8; ++c) acc[c] = 0.f;
    float den = 0.f;

    int idx = lo + g;
    bool have = (idx + 4 < hi);
    int sa = 0, sb = 0;
    uint4 ba = make_uint4(0, 0, 0, 0), bb = make_uint4(0, 0, 0, 0);
    float sva = 0.f, svb = 0.f;
    if (have) {
        sa = csr[idx]; sb = csr[idx + 4];
        ba = h1q[(size_t)sa * 16 + q];
        bb = h1q[(size_t)sb * 16 + q];
        sva = __uint_as_float((unsigned)s1b[(size_t)sa * 8 + hb] << 16);
        svb = __uint_as_float((unsigned)s1b[(size_t)sb * 8 + hb] << 16);
    }
    while (have) {
        int nidx = idx + 8;
        bool nhave = (nidx + 4 < hi);
        int na = 0, nb = 0;
        uint4 nba = make_uint4(0, 0, 0, 0), nbb = make_uint4(0, 0, 0, 0);
        float nsa = 0.f, nsb = 0.f;
        if (nhave) {
            na = csr[nidx]; nb = csr[nidx + 4];
            nba = h1q[(size_t)na * 16 + q];
            nbb = h1q[(size_t)nb * 16 + q];
            nsa = __uint_as_float((unsigned)s1b[(size_t)na * 8 + hb] << 16);
            nsb = __uint_as_float((unsigned)s1b[(size_t)nb * 8 + hb] << 16);
        }
        float w0 = __expf(lrelu(sva + dvh));
        float w1 = __expf(lrelu(svb + dvh));
        den += w0 + w1;
        unsigned int wp;
        asm("v_cvt_pk_bf16_f32 %0, %1, %2" : "=v"(wp) : "v"(w0), "v"(w1));
        unsigned int p0, p1;
        p0 = __builtin_amdgcn_perm(bb.x, ba.x, 0x05040100u);
        p1 = __builtin_amdgcn_perm(bb.x, ba.x, 0x07060302u);
        acc[0] = dot2bf(wp, p0, acc[0]);
        acc[1] = dot2bf(wp, p1, acc[1]);
        p0 = __builtin_amdgcn_perm(bb.y, ba.y, 0x05040100u);
        p1 = __builtin_amdgcn_perm(bb.y, ba.y, 0x07060302u);
        acc[2] = dot2bf(wp, p0, acc[2]);
        acc[3] = dot2bf(wp, p1, acc[3]);
        p0 = __builtin_amdgcn_perm(bb.z, ba.z, 0x05040100u);
        p1 = __builtin_amdgcn_perm(bb.z, ba.z, 0x07060302u);
        acc[4] = dot2bf(wp, p0, acc[4]);
        acc[5] = dot2bf(wp, p1, acc[5]);
        p0 = __builtin_amdgcn_perm(bb.w, ba.w, 0x05040100u);
        p1 = __builtin_amdgcn_perm(bb.w, ba.w, 0x07060302u);
        acc[6] = dot2bf(wp, p0, acc[6]);
        acc[7] = dot2bf(wp, p1, acc[7]);
        sa = na; sb = nb; ba = nba; bb = nbb; sva = nsa; svb = nsb;
        idx = nidx; have = nhave;
    }
    if (idx < hi) {
        int sc = csr[idx];
        uint4 bv = h1q[(size_t)sc * 16 + q];
        float sv = __uint_as_float((unsigned)s1b[(size_t)sc * 8 + hb] << 16);
        float w = __expf(lrelu(sv + dvh));
        den += w;
        acc[0] = fmaf(w, bflo(bv.x), acc[0]);
        acc[1] = fmaf(w, bfhi(bv.x), acc[1]);
        acc[2] = fmaf(w, bflo(bv.y), acc[2]);
        acc[3] = fmaf(w, bfhi(bv.y), acc[3]);
        acc[4] = fmaf(w, bflo(bv.z), acc[4]);
        acc[5] = fmaf(w, bfhi(bv.z), acc[5]);
        acc[6] = fmaf(w, bflo(bv.w), acc[6]);
        acc[7] = fmaf(w, bfhi(bv.w), acc[7]);
    }
#pragma unroll
    for (int c = 0; c < 8; ++c) {
        acc[c] += __shfl_xor(acc[c], 16, 64);
        acc[c] += __shfl_xor(acc[c], 32, 64);
    }
    den += __shfl_xor(den, 16, 64);
    den += __shfl_xor(den, 32, 64);

    if (l < 16) {
        float r = 1.f / den;
        float vv[8];
#pragma unroll
        for (int c = 0; c < 8; ++c) {
            float v = acc[c] * r + b1[8 * q + c];
            vv[c] = v > 0.f ? v : expm1f(v);
            esh[wv][8 * q + c] = vv[c];
        }
        float4* ep = (float4*)(emb + (size_t)node * 128);
        ep[2 * q]     = make_float4(vv[0], vv[1], vv[2], vv[3]);
        ep[2 * q + 1] = make_float4(vv[4], vv[5], vv[6], vv[7]);
    }
    __syncthreads();

    // fused gemm2: interleaved channel partition, conflict-free LDS reads
    int j = l & 15, part = l >> 4;
    float o = 0.f;
#pragma unroll
    for (int cc = 0; cc < 32; ++cc) {
        int c = 4 * cc + part;
        o = fmaf(esh[wv][c], W2[c * 16 + j], o);
    }
    o += __shfl_xor(o, 16, 64);
    o += __shfl_xor(o, 32, 64);
    float ps = o * as2[j], pd = o * ad2[j];
#pragma unroll
    for (int ofs = 1; ofs < 16; ofs <<= 1) {
        ps += __shfl_xor(ps, ofs, 16);
        pd += __shfl_xor(pd, ofs, 16);
    }
    if (l < 16) h2s[(size_t)node * 16 + j] = f2bf(o);
    if (l == 0) { s2[node] = ps; d2v[node] = pd; }
}

// ---------------- layer 2 aggregate + log_softmax (pairs, pipelined) --------
__global__ __launch_bounds__(256) void k_l2(
    const int* __restrict__ perm,
    const int* __restrict__ off, const int* __restrict__ csr,
    const float* __restrict__ s2, const float* __restrict__ d2,
    const unsigned int* __restrict__ h2w, const float* __restrict__ b2,
    float* __restrict__ logits) {
    int t = threadIdx.x;
    int node = perm[(blockIdx.x << 2) + (t >> 6)];
    int l = t & 63;
    int g = l >> 3, p = l & 7;
    int lo = off[node], hi = off[node + 1];
    float dv = d2[node];

    float ax = 0.f, ay = 0.f, den = 0.f;
    int idx = lo + g;
    int him = hi - 1;
    if (idx + 8 < hi) {
        int s0 = csr[idx], s1i = csr[idx + 8];
        unsigned int pa = h2w[(size_t)s0 * 8 + p];
        unsigned int pb = h2w[(size_t)s1i * 8 + p];
        float wa = s2[s0], wb = s2[s1i];
        int ia = csr[min(idx + 16, him)];
        int ib = csr[min(idx + 24, him)];
        while (true) {
            unsigned int npa = h2w[(size_t)ia * 8 + p];
            unsigned int npb = h2w[(size_t)ib * 8 + p];
            float nwa = s2[ia], nwb = s2[ib];
            int nia = csr[min(idx + 32, him)];
            int nib = csr[min(idx + 40, him)];
            float w0 = __expf(lrelu(wa + dv));
            float w1 = __expf(lrelu(wb + dv));
            den += w0 + w1;
            unsigned int wp;
            asm("v_cvt_pk_bf16_f32 %0, %1, %2" : "=v"(wp) : "v"(w0), "v"(w1));
            unsigned int p0 = __builtin_amdgcn_perm(pb, pa, 0x05040100u);
            unsigned int p1 = __builtin_amdgcn_perm(pb, pa, 0x07060302u);
            ax = dot2bf(wp, p0, ax);
            ay = dot2bf(wp, p1, ay);
            idx += 16;
            if (idx + 8 >= hi) break;
            pa = npa; pb = npb; wa = nwa; wb = nwb;
            ia = nia; ib = nib;
        }
    }
    if (idx < hi) {   // one leftover edge
        int s = csr[idx];
        float w = __expf(lrelu(s2[s] + dv));
        den += w;
        unsigned int bv = h2w[(size_t)s * 8 + p];
        ax = fmaf(w, bflo(bv), ax);
        ay = fmaf(w, bfhi(bv), ay);
    }
#pragma unroll
    for (int ofs = 8; ofs < 64; ofs <<= 1) {
        ax += __shfl_xor(ax, ofs, 64);
        ay += __shfl_xor(ay, ofs, 64);
        den += __shfl_xor(den, ofs, 64);
    }
    float r = 1.f / den;
    float v0 = ax * r + b2[2 * p], v1 = ay * r + b2[2 * p + 1];
    float mm = fmaxf(v0, v1);
#pragma unroll
    for (int ofs = 1; ofs < 8; ofs <<= 1) mm = fmaxf(mm, __shfl_xor(mm, ofs, 8));
    float sm = __expf(v0 - mm) + __expf(v1 - mm);
#pragma unroll
    for (int ofs = 1; ofs < 8; ofs <<= 1) sm += __shfl_xor(sm, ofs, 8);
    if (g == 0) {
        float ls = logf(sm);
        logits[node * 16 + 2 * p]     = v0 - mm - ls;
        logits[node * 16 + 2 * p + 1] = v1 - mm - ls;
    }
}

extern "C" void kernel_launch(void* const* d_in, const int* in_sizes, int n_in,
                              void* d_out, int out_size, void* d_ws, size_t ws_size,
                              hipStream_t stream) {
    const float* x   = (const float*)d_in[0];
    const int*   ei  = (const int*)d_in[1];
    const float* W1  = (const float*)d_in[2];
    const float* as1 = (const float*)d_in[3];
    const float* ad1 = (const float*)d_in[4];
    const float* b1  = (const float*)d_in[5];
    const float* W2  = (const float*)d_in[6];
    const float* as2 = (const float*)d_in[7];
    const float* ad2 = (const float*)d_in[8];
    const float* b2  = (const float*)d_in[9];

    float* out    = (float*)d_out;
    float* logits = out;                          // [N,16]
    float* emb    = out + (size_t)N_NODES * 16;   // [N,128]

    float* ws    = (float*)d_ws;
    unsigned int* h1w = (unsigned int*)ws;                    // N*64 words (bf16 x2)
    int2*  coo   = (int2*)(h1w + (size_t)N_NODES * 64);      // NBUCK*CAP_B
    unsigned short* s1b = (unsigned short*)(coo + (size_t)NBUCK * CAP_B); // N*8
    float* d1    = (float*)(s1b + (size_t)N_NODES * 8);       // N*8
    unsigned short* h2s = (unsigned short*)(d1 + (size_t)N_NODES * 8);   // N*16
    float* s2    = (float*)(h2s + (size_t)N_NODES * 16);      // N
    float* d2v   = s2 + (size_t)N_NODES;
    int*   offs  = (int*)(d2v + (size_t)N_NODES);             // N+2
    int*   csr   = offs + N_NODES + 2;                        // ETOT
    int*   gcur  = csr + ETOT;                                // NBUCK
    int*   dhist = gcur + NBUCK;                              // DBINS
    int*   bbase = dhist + DBINS;                             // NBUCK
    int*   dcur  = bbase + NBUCK;                             // DBINS
    int*   perm  = dcur + DBINS;                              // N
    unsigned short* wtg = (unsigned short*)(perm + N_NODES);  // 128*128 bf16

    const int* srcp = ei;
    const int* dstp = ei + E_EDGES;

    hipMemsetAsync(gcur, 0, (size_t)(NBUCK + DBINS) * sizeof(int), stream);

    k_wt<<<64, 256, 0, stream>>>(W1, wtg);
    k_parBin<<<NBIN + G_A, 256, 0, stream>>>(srcp, dstp, gcur, coo,
                                             x, wtg, as1, ad1,
                                             (__hip_bfloat16*)h1w, s1b, d1);
    k_scanb<<<1, 256, 0, stream>>>(gcur, bbase, offs);
    k_parFine<<<NBUCK + G_B, 256, 0, stream>>>(coo, gcur, bbase, offs, csr,
                                               x, wtg, as1, ad1,
                                               (__hip_bfloat16*)h1w, s1b, d1);

    k_dcnt<<<NODE_BLK, 256, 0, stream>>>(offs, dhist);
    k_dbase<<<1, 64, 0, stream>>>(dhist, dcur);
    k_dscat<<<NODE_BLK, 256, 0, stream>>>(offs, dcur, perm);

    k_l1<<<N_NODES / 4, 256, 0, stream>>>(perm, offs, csr, s1b, d1,
                                          (const uint4*)h1w, b1, emb,
                                          W2, as2, ad2, h2s, s2, d2v);

    k_l2<<<N_NODES / 4, 256, 0, stream>>>(perm, offs, csr, s2, d2v,
                                          (const unsigned int*)h2s, b2, logits);
}

// Round 25
// 244.743 us; speedup vs baseline: 1.0635x; 1.0635x over previous
//
#include <hip/hip_runtime.h>
#include <hip/hip_bf16.h>
#include <math.h>

#define N_NODES 100000
#define E_EDGES 1600000
#define ETOT    (E_EDGES + N_NODES)
#define NEG     0.2f

// bucketed CSR build
#define SH        8
#define NBUCK     ((N_NODES + 255) >> 8)          // 391
#define BIN_TILE  4096
#define NBIN      ((E_EDGES + BIN_TILE - 1) / BIN_TILE)  // 391
#define CAP_B     5120                            // per-bucket COO capacity

#define NMFMA     ((N_NODES + 63) / 64)           // 1563
#define G_A       782                             // gemm blocks fused with bin
#define G_B       (NMFMA - G_A)                   // 781, fused with fine

typedef __attribute__((ext_vector_type(8))) short bf16x8;
typedef __attribute__((ext_vector_type(4))) float f32x4;
typedef __attribute__((ext_vector_type(2))) short bf16p;

__device__ inline float lrelu(float x) { return x > 0.f ? x : NEG * x; }
__device__ inline float bflo(unsigned int b) { return __uint_as_float(b << 16); }
__device__ inline float bfhi(unsigned int b) { return __uint_as_float(b & 0xFFFF0000u); }
__device__ inline unsigned short f2bf(float f) {   // RNE bf16 bits
    unsigned int u = __float_as_uint(f);
    return (unsigned short)((u + 0x7FFFu + ((u >> 16) & 1u)) >> 16);
}

// dot of 2 bf16 pairs with f32 accumulate
__device__ inline float dot2bf(unsigned int wp, unsigned int hp, float c) {
#if __has_builtin(__builtin_amdgcn_fdot2_f32_bf16)
    return __builtin_amdgcn_fdot2_f32_bf16(__builtin_bit_cast(bf16p, wp),
                                           __builtin_bit_cast(bf16p, hp),
                                           c, false);
#else
    return fmaf(bflo(wp), bflo(hp), fmaf(bfhi(wp), bfhi(hp), c));
#endif
}

// exclusive scan over 256 threads: wave shfl scan + 1 barrier. wscr = int[4].
__device__ inline int exscan256(int v, int* wscr, int t) {
    int lane = t & 63, wid = t >> 6;
    int incl = v;
#pragma unroll
    for (int ofs = 1; ofs < 64; ofs <<= 1) {
        int u = __shfl_up(incl, ofs, 64);
        if (lane >= ofs) incl += u;
    }
    if (lane == 63) wscr[wid] = incl;
    __syncthreads();
    int wpre = 0;
#pragma unroll
    for (int w = 0; w < 4; ++w) wpre += (w < wid) ? wscr[w] : 0;
    return wpre + incl - v;
}

// ---------------- W1^T -> bf16 (one-off, 32 KB) -----------------------------
__global__ __launch_bounds__(256) void k_wt(const float* __restrict__ W,
                                            unsigned short* __restrict__ wtg) {
    int t = blockIdx.x * 256 + threadIdx.x;   // t = n*128 + k
    if (t >= 128 * 128) return;
    int n = t >> 7, k = t & 127;
    wtg[t] = f2bf(W[k * 128 + n]);
}

// ---------------- gemm1 role (device fn): 64 nodes per block ----------------
__device__ __forceinline__ void gemm1_role(
    int n0, int t, unsigned short (*xb)[136],
    const float* __restrict__ x, const unsigned short* __restrict__ wtg,
    const float* __restrict__ asrc, const float* __restrict__ adst,
    __hip_bfloat16* __restrict__ h1b, unsigned short* __restrict__ s1b,
    float* __restrict__ d1) {
#pragma unroll
    for (int i = 0; i < 8; ++i) {
        int i4 = t + i * 256;
        int r = i4 >> 5;
        int c = (i4 & 31) * 4;
        float4 v = make_float4(0.f, 0.f, 0.f, 0.f);
        if (n0 + r < N_NODES) v = *(const float4*)(x + (size_t)(n0 + r) * 128 + c);
        xb[r][c + 0] = f2bf(v.x);
        xb[r][c + 1] = f2bf(v.y);
        xb[r][c + 2] = f2bf(v.z);
        xb[r][c + 3] = f2bf(v.w);
    }
    __syncthreads();

    int l = t & 63, wv = t >> 6;
    int col = l & 15, q4 = l >> 4;
    int rbase = wv * 16;
    int koff = q4 * 8;

    bf16x8 a[4];
#pragma unroll
    for (int st = 0; st < 4; ++st)
        a[st] = *(const bf16x8*)&xb[rbase + col][st * 32 + koff];

    int nodeb = n0 + rbase + q4 * 4;
#pragma unroll
    for (int nt = 0; nt < 8; ++nt) {
        f32x4 acc = {0.f, 0.f, 0.f, 0.f};
        const unsigned short* wrow = wtg + (size_t)(nt * 16 + col) * 128 + koff;
#pragma unroll
        for (int st = 0; st < 4; ++st) {
            bf16x8 b = *(const bf16x8*)(wrow + st * 32);
            acc = __builtin_amdgcn_mfma_f32_16x16x32_bf16(a[st], b, acc, 0, 0, 0);
        }
        float as_v = asrc[nt * 16 + col];
        float ad_v = adst[nt * 16 + col];
#pragma unroll
        for (int r = 0; r < 4; ++r) {
            int node = nodeb + r;
            if (node < N_NODES)
                h1b[(size_t)node * 128 + nt * 16 + col] = __float2bfloat16(acc[r]);
            float ps = acc[r] * as_v, pd = acc[r] * ad_v;
#pragma unroll
            for (int ofs = 1; ofs < 16; ofs <<= 1) {
                ps += __shfl_xor(ps, ofs, 64);
                pd += __shfl_xor(pd, ofs, 64);
            }
            if (col == 0 && node < N_NODES) {
                s1b[node * 8 + nt] = f2bf(ps);
                d1[node * 8 + nt] = pd;
            }
        }
    }
}

// ---------------- kernel: bin (bucket-major COO) || gemm1 part A ------------
union SmemBin {
    struct {
        int2 st[BIN_TILE];
        int  hist[NBUCK + 1];
        int  lstart[NBUCK];
        int  gbase[NBUCK];
        int  wscr[4];
    } b;
    unsigned short xb[64][136];
};

__global__ __launch_bounds__(256) void k_parBin(
    const int* __restrict__ src, const int* __restrict__ dst,
    int* __restrict__ gcur, int2* __restrict__ coo,
    const float* __restrict__ x, const unsigned short* __restrict__ wtg,
    const float* __restrict__ asrc, const float* __restrict__ adst,
    __hip_bfloat16* __restrict__ h1b, unsigned short* __restrict__ s1b,
    float* __restrict__ d1) {
    __shared__ SmemBin sm;
    int bid = blockIdx.x, t = threadIdx.x;
    bool isBin = (bid % 3 == 0) && (bid / 3 < NBIN);
    if (!isBin) {                       // gemm role, gid 0..G_A-1
        int gid = bid - bid / 3 - 1;
        gemm1_role(gid * 64, t, sm.xb, x, wtg, asrc, adst, h1b, s1b, d1);
        return;
    }
    int wb = bid / 3;                   // bin tile 0..NBIN-1
    int e0 = wb * BIN_TILE;
    int nE = min(BIN_TILE, E_EDGES - e0);
    for (int i = t; i <= NBUCK; i += 256) sm.b.hist[i] = 0;
    __syncthreads();
    for (int i = t; i < nE; i += 256)
        atomicAdd(&sm.b.hist[dst[e0 + i] >> SH], 1);
    __syncthreads();
    int i0 = 2 * t, i1 = 2 * t + 1;
    int h0 = (i0 < NBUCK) ? sm.b.hist[i0] : 0;
    int h1v = (i1 < NBUCK) ? sm.b.hist[i1] : 0;
    int s = h0 + h1v;
    int pre = exscan256(s, sm.b.wscr, t);
    __syncthreads();
    if (i0 < NBUCK) sm.b.hist[i0] = pre;
    if (i1 < NBUCK) sm.b.hist[i1] = pre + h0;
    if (t == 255) sm.b.hist[NBUCK] = pre + s;
    __syncthreads();
    for (int i = t; i < NBUCK; i += 256) {
        int st_ = sm.b.hist[i];
        int cnt = sm.b.hist[i + 1] - st_;
        sm.b.lstart[i] = st_;
        if (cnt > 0) sm.b.gbase[i] = i * CAP_B + atomicAdd(&gcur[i], cnt);
    }
    __syncthreads();
    for (int i = t; i < nE; i += 256) {
        int sv = src[e0 + i], dv = dst[e0 + i];
        int p = atomicAdd(&sm.b.hist[dv >> SH], 1);
        sm.b.st[p] = make_int2(sv, dv);
    }
    __syncthreads();
    for (int i = t; i < nE; i += 256) {
        int2 e = sm.b.st[i];
        int b2 = e.y >> SH;
        int slot = sm.b.gbase[b2] + (i - sm.b.lstart[b2]);
        slot = min(slot, (b2 + 1) * CAP_B - 1);   // overflow clamp
        coo[slot] = e;
    }
}

// ---------------- scanb: 391 bucket totals -> bbase; off[N]=ETOT ------------
__global__ __launch_bounds__(256) void k_scanb(const int* __restrict__ gcur,
                                               int* __restrict__ bbase,
                                               int* __restrict__ off) {
    __shared__ int wscr[4];
    int t = threadIdx.x;
    int i0 = 2 * t, i1 = 2 * t + 1;
    int a = 0, b = 0;
    if (i0 < NBUCK) a = min(gcur[i0], CAP_B) + min(256, N_NODES - (i0 << SH));
    if (i1 < NBUCK) b = min(gcur[i1], CAP_B) + min(256, N_NODES - (i1 << SH));
    int s = a + b;
    int pre = exscan256(s, wscr, t);
    if (i0 < NBUCK) bbase[i0] = pre;
    if (i1 < NBUCK) bbase[i1] = pre + a;
    if (t == 0) off[N_NODES] = ETOT;
}

// ---------------- kernel: fine (LDS reorder) || gemm1 part B ----------------
union SmemFine {
    struct {
        int ldeg[256];
        int lsrc[CAP_B + 256];
        int wscr[4];
    } f;
    unsigned short xb[64][136];
};

__global__ __launch_bounds__(256) void k_parFine(
    const int2* __restrict__ coo, const int* __restrict__ gcur,
    const int* __restrict__ bbase, int* __restrict__ off,
    int* __restrict__ csr,
    const float* __restrict__ x, const unsigned short* __restrict__ wtg,
    const float* __restrict__ asrc, const float* __restrict__ adst,
    __hip_bfloat16* __restrict__ h1b, unsigned short* __restrict__ s1b,
    float* __restrict__ d1) {
    __shared__ SmemFine sm;
    int bid = blockIdx.x, t = threadIdx.x;
    bool isFine = (bid % 3 == 0) && (bid / 3 < NBUCK);
    if (!isFine) {                      // gemm role, gid 0..G_B-1
        int gid = bid - bid / 3 - 1;
        gemm1_role((G_A + gid) * 64, t, sm.xb, x, wtg, asrc, adst,
                   h1b, s1b, d1);
        return;
    }
    int b = bid / 3;
    int n0 = b << SH;
    int nn = min(256, N_NODES - n0);
    int ecnt = min(gcur[b], CAP_B);
    int base = bbase[b];
    const int2* seg = coo + (size_t)b * CAP_B;

    sm.f.ldeg[t] = 0;
    __syncthreads();
    for (int i = t; i < ecnt; i += 256)
        atomicAdd(&sm.f.ldeg[seg[i].y - n0], 1);
    __syncthreads();
    int d = (t < nn) ? sm.f.ldeg[t] + 1 : 0;   // +1 self-loop
    int myoff = exscan256(d, sm.f.wscr, t);
    __syncthreads();
    if (t < nn) {
        off[n0 + t] = base + myoff;
        sm.f.lsrc[myoff] = n0 + t;
        sm.f.ldeg[t] = myoff + 1;
    }
    __syncthreads();
    for (int i = t; i < ecnt; i += 256) {
        int2 e = seg[i];
        int p = atomicAdd(&sm.f.ldeg[e.y - n0], 1);
        sm.f.lsrc[p] = e.x;
    }
    __syncthreads();
    int tot = ecnt + nn;
    for (int i = t; i < tot; i += 256)
        csr[base + i] = sm.f.lsrc[i];
}

// ---------------- layer 1 softmax-aggregate + fused gemm2 (LDS handoff) -----
// block 256 = 4 nodes x 1 wave; dot2 pairs with 1-deep prefetch; epilogue
// stages the node's emb row in LDS with bank-remap idx = 9*(c>>3) + (c&7)
// (write banks 9q mod 32 all distinct; reads consecutive) -> conflict-free.
__global__ __launch_bounds__(256) void k_l1(
    const int* __restrict__ off, const int* __restrict__ csr,
    const unsigned short* __restrict__ s1b, const float* __restrict__ d1,
    const uint4* __restrict__ h1q, const float* __restrict__ b1,
    float* __restrict__ emb,
    const float* __restrict__ W2, const float* __restrict__ as2,
    const float* __restrict__ ad2, unsigned short* __restrict__ h2s,
    float* __restrict__ s2, float* __restrict__ d2v) {
    __shared__ float esh[4][144];
    int t = threadIdx.x;
    int node = blockIdx.x * 4 + (t >> 6);
    int wv = t >> 6;
    int l = t & 63;
    int g = l >> 4, q = l & 15;
    int hb = q >> 1;
    int lo = off[node], hi = off[node + 1];
    float dvh = d1[node * 8 + hb];

    float acc[8];
#pragma unroll
    for (int c = 0; c < 8; ++c) acc[c] = 0.f;
    float den = 0.f;

    int idx = lo + g;
    bool have = (idx + 4 < hi);
    int sa = 0, sb = 0;
    uint4 ba = make_uint4(0, 0, 0, 0), bb = make_uint4(0, 0, 0, 0);
    float sva = 0.f, svb = 0.f;
    if (have) {
        sa = csr[idx]; sb = csr[idx + 4];
        ba = h1q[(size_t)sa * 16 + q];
        bb = h1q[(size_t)sb * 16 + q];
        sva = __uint_as_float((unsigned)s1b[(size_t)sa * 8 + hb] << 16);
        svb = __uint_as_float((unsigned)s1b[(size_t)sb * 8 + hb] << 16);
    }
    while (have) {
        int nidx = idx + 8;
        bool nhave = (nidx + 4 < hi);
        int na = 0, nb = 0;
        uint4 nba = make_uint4(0, 0, 0, 0), nbb = make_uint4(0, 0, 0, 0);
        float nsa = 0.f, nsb = 0.f;
        if (nhave) {
            na = csr[nidx]; nb = csr[nidx + 4];
            nba = h1q[(size_t)na * 16 + q];
            nbb = h1q[(size_t)nb * 16 + q];
            nsa = __uint_as_float((unsigned)s1b[(size_t)na * 8 + hb] << 16);
            nsb = __uint_as_float((unsigned)s1b[(size_t)nb * 8 + hb] << 16);
        }
        float w0 = __expf(lrelu(sva + dvh));
        float w1 = __expf(lrelu(svb + dvh));
        den += w0 + w1;
        unsigned int wp;
        asm("v_cvt_pk_bf16_f32 %0, %1, %2" : "=v"(wp) : "v"(w0), "v"(w1));
        unsigned int p0, p1;
        p0 = __builtin_amdgcn_perm(bb.x, ba.x, 0x05040100u);
        p1 = __builtin_amdgcn_perm(bb.x, ba.x, 0x07060302u);
        acc[0] = dot2bf(wp, p0, acc[0]);
        acc[1] = dot2bf(wp, p1, acc[1]);
        p0 = __builtin_amdgcn_perm(bb.y, ba.y, 0x05040100u);
        p1 = __builtin_amdgcn_perm(bb.y, ba.y, 0x07060302u);
        acc[2] = dot2bf(wp, p0, acc[2]);
        acc[3] = dot2bf(wp, p1, acc[3]);
        p0 = __builtin_amdgcn_perm(bb.z, ba.z, 0x05040100u);
        p1 = __builtin_amdgcn_perm(bb.z, ba.z, 0x07060302u);
        acc[4] = dot2bf(wp, p0, acc[4]);
        acc[5] = dot2bf(wp, p1, acc[5]);
        p0 = __builtin_amdgcn_perm(bb.w, ba.w, 0x05040100u);
        p1 = __builtin_amdgcn_perm(bb.w, ba.w, 0x07060302u);
        acc[6] = dot2bf(wp, p0, acc[6]);
        acc[7] = dot2bf(wp, p1, acc[7]);
        sa = na; sb = nb; ba = nba; bb = nbb; sva = nsa; svb = nsb;
        idx = nidx; have = nhave;
    }
    if (idx < hi) {
        int sc = csr[idx];
        uint4 bv = h1q[(size_t)sc * 16 + q];
        float sv = __uint_as_float((unsigned)s1b[(size_t)sc * 8 + hb] << 16);
        float w = __expf(lrelu(sv + dvh));
        den += w;
        acc[0] = fmaf(w, bflo(bv.x), acc[0]);
        acc[1] = fmaf(w, bfhi(bv.x), acc[1]);
        acc[2] = fmaf(w, bflo(bv.y), acc[2]);
        acc[3] = fmaf(w, bfhi(bv.y), acc[3]);
        acc[4] = fmaf(w, bflo(bv.z), acc[4]);
        acc[5] = fmaf(w, bfhi(bv.z), acc[5]);
        acc[6] = fmaf(w, bflo(bv.w), acc[6]);
        acc[7] = fmaf(w, bfhi(bv.w), acc[7]);
    }
#pragma unroll
    for (int c = 0; c < 8; ++c) {
        acc[c] += __shfl_xor(acc[c], 16, 64);
        acc[c] += __shfl_xor(acc[c], 32, 64);
    }
    den += __shfl_xor(den, 16, 64);
    den += __shfl_xor(den, 32, 64);

    if (l < 16) {
        float r = 1.f / den;
        float vv[8];
#pragma unroll
        for (int c = 0; c < 8; ++c) {
            float v = acc[c] * r + b1[8 * q + c];
            vv[c] = v > 0.f ? v : expm1f(v);
            esh[wv][9 * q + c] = vv[c];    // remapped: conflict-free banks
        }
        float4* ep = (float4*)(emb + (size_t)node * 128);
        ep[2 * q]     = make_float4(vv[0], vv[1], vv[2], vv[3]);
        ep[2 * q + 1] = make_float4(vv[4], vv[5], vv[6], vv[7]);
    }
    __syncthreads();

    // fused gemm2: interleaved channel partition, conflict-free LDS reads
    int j = l & 15, part = l >> 4;
    float o = 0.f;
#pragma unroll
    for (int cc = 0; cc < 32; ++cc) {
        int c = 4 * cc + part;
        o = fmaf(esh[wv][9 * (c >> 3) + (c & 7)], W2[c * 16 + j], o);
    }
    o += __shfl_xor(o, 16, 64);
    o += __shfl_xor(o, 32, 64);
    float ps = o * as2[j], pd = o * ad2[j];
#pragma unroll
    for (int ofs = 1; ofs < 16; ofs <<= 1) {
        ps += __shfl_xor(ps, ofs, 16);
        pd += __shfl_xor(pd, ofs, 16);
    }
    if (l < 16) h2s[(size_t)node * 16 + j] = f2bf(o);
    if (l == 0) { s2[node] = ps; d2v[node] = pd; }
}

// ---------------- layer 2 aggregate + log_softmax (pairs, pipelined) --------
__global__ __launch_bounds__(256) void k_l2(
    const int* __restrict__ off, const int* __restrict__ csr,
    const float* __restrict__ s2, const float* __restrict__ d2,
    const unsigned int* __restrict__ h2w, const float* __restrict__ b2,
    float* __restrict__ logits) {
    int t = threadIdx.x;
    int node = blockIdx.x * 4 + (t >> 6);
    int l = t & 63;
    int g = l >> 3, p = l & 7;
    int lo = off[node], hi = off[node + 1];
    float dv = d2[node];

    float ax = 0.f, ay = 0.f, den = 0.f;
    int idx = lo + g;
    int him = hi - 1;
    if (idx + 8 < hi) {
        int s0 = csr[idx], s1i = csr[idx + 8];
        unsigned int pa = h2w[(size_t)s0 * 8 + p];
        unsigned int pb = h2w[(size_t)s1i * 8 + p];
        float wa = s2[s0], wb = s2[s1i];
        int ia = csr[min(idx + 16, him)];
        int ib = csr[min(idx + 24, him)];
        while (true) {
            unsigned int npa = h2w[(size_t)ia * 8 + p];
            unsigned int npb = h2w[(size_t)ib * 8 + p];
            float nwa = s2[ia], nwb = s2[ib];
            int nia = csr[min(idx + 32, him)];
            int nib = csr[min(idx + 40, him)];
            float w0 = __expf(lrelu(wa + dv));
            float w1 = __expf(lrelu(wb + dv));
            den += w0 + w1;
            unsigned int wp;
            asm("v_cvt_pk_bf16_f32 %0, %1, %2" : "=v"(wp) : "v"(w0), "v"(w1));
            unsigned int p0 = __builtin_amdgcn_perm(pb, pa, 0x05040100u);
            unsigned int p1 = __builtin_amdgcn_perm(pb, pa, 0x07060302u);
            ax = dot2bf(wp, p0, ax);
            ay = dot2bf(wp, p1, ay);
            idx += 16;
            if (idx + 8 >= hi) break;
            pa = npa; pb = npb; wa = nwa; wb = nwb;
            ia = nia; ib = nib;
        }
    }
    if (idx < hi) {   // one leftover edge
        int s = csr[idx];
        float w = __expf(lrelu(s2[s] + dv));
        den += w;
        unsigned int bv = h2w[(size_t)s * 8 + p];
        ax = fmaf(w, bflo(bv), ax);
        ay = fmaf(w, bfhi(bv), ay);
    }
#pragma unroll
    for (int ofs = 8; ofs < 64; ofs <<= 1) {
        ax += __shfl_xor(ax, ofs, 64);
        ay += __shfl_xor(ay, ofs, 64);
        den += __shfl_xor(den, ofs, 64);
    }
    float r = 1.f / den;
    float v0 = ax * r + b2[2 * p], v1 = ay * r + b2[2 * p + 1];
    float mm = fmaxf(v0, v1);
#pragma unroll
    for (int ofs = 1; ofs < 8; ofs <<= 1) mm = fmaxf(mm, __shfl_xor(mm, ofs, 8));
    float sm = __expf(v0 - mm) + __expf(v1 - mm);
#pragma unroll
    for (int ofs = 1; ofs < 8; ofs <<= 1) sm += __shfl_xor(sm, ofs, 8);
    if (g == 0) {
        float ls = logf(sm);
        logits[node * 16 + 2 * p]     = v0 - mm - ls;
        logits[node * 16 + 2 * p + 1] = v1 - mm - ls;
    }
}

extern "C" void kernel_launch(void* const* d_in, const int* in_sizes, int n_in,
                              void* d_out, int out_size, void* d_ws, size_t ws_size,
                              hipStream_t stream) {
    const float* x   = (const float*)d_in[0];
    const int*   ei  = (const int*)d_in[1];
    const float* W1  = (const float*)d_in[2];
    const float* as1 = (const float*)d_in[3];
    const float* ad1 = (const float*)d_in[4];
    const float* b1  = (const float*)d_in[5];
    const float* W2  = (const float*)d_in[6];
    const float* as2 = (const float*)d_in[7];
    const float* ad2 = (const float*)d_in[8];
    const float* b2  = (const float*)d_in[9];

    float* out    = (float*)d_out;
    float* logits = out;                          // [N,16]
    float* emb    = out + (size_t)N_NODES * 16;   // [N,128]

    float* ws    = (float*)d_ws;
    unsigned int* h1w = (unsigned int*)ws;                    // N*64 words (bf16 x2)
    int2*  coo   = (int2*)(h1w + (size_t)N_NODES * 64);      // NBUCK*CAP_B
    unsigned short* s1b = (unsigned short*)(coo + (size_t)NBUCK * CAP_B); // N*8
    float* d1    = (float*)(s1b + (size_t)N_NODES * 8);       // N*8
    unsigned short* h2s = (unsigned short*)(d1 + (size_t)N_NODES * 8);   // N*16
    float* s2    = (float*)(h2s + (size_t)N_NODES * 16);      // N
    float* d2v   = s2 + (size_t)N_NODES;
    int*   offs  = (int*)(d2v + (size_t)N_NODES);             // N+2
    int*   csr   = offs + N_NODES + 2;                        // ETOT
    int*   gcur  = csr + ETOT;                                // NBUCK
    int*   bbase = gcur + NBUCK;                              // NBUCK
    unsigned short* wtg = (unsigned short*)(bbase + NBUCK);   // 128*128 bf16

    const int* srcp = ei;
    const int* dstp = ei + E_EDGES;

    hipMemsetAsync(gcur, 0, (size_t)NBUCK * sizeof(int), stream);

    k_wt<<<64, 256, 0, stream>>>(W1, wtg);
    k_parBin<<<NBIN + G_A, 256, 0, stream>>>(srcp, dstp, gcur, coo,
                                             x, wtg, as1, ad1,
                                             (__hip_bfloat16*)h1w, s1b, d1);
    k_scanb<<<1, 256, 0, stream>>>(gcur, bbase, offs);
    k_parFine<<<NBUCK + G_B, 256, 0, stream>>>(coo, gcur, bbase, offs, csr,
                                               x, wtg, as1, ad1,
                                               (__hip_bfloat16*)h1w, s1b, d1);

    k_l1<<<N_NODES / 4, 256, 0, stream>>>(offs, csr, s1b, d1,
                                          (const uint4*)h1w, b1, emb,
                                          W2, as2, ad2, h2s, s2, d2v);

    k_l2<<<N_NODES / 4, 256, 0, stream>>>(offs, csr, s2, d2v,
                                          (const unsigned int*)h2s, b2, logits);
}